// Round 14
// baseline (46.033 us; speedup 1.0000x reference)
//
#include <hip/hip_runtime.h>
#include <cstdint>
#include <cstddef>

#define S      4096
#define BATCH  16
#define BLK    256
#define YSPAN  1024                 // inner range per block (4 slabs)
#define NT16   (YSPAN / 16)         // 64 tiles of 16 inner-points
#define ROWS_PER_BLOCK 64           // 4 waves x 16 rows
#define XC_N   (S / ROWS_PER_BLOCK) // 64 outer-chunks
#define YC_N   (S / YSPAN)          // 4 inner-slabs

typedef _Float16 half8   __attribute__((ext_vector_type(8)));
typedef float    floatx4 __attribute__((ext_vector_type(4)));

__device__ inline unsigned pack2(_Float16 lo, _Float16 hi) {
    unsigned short a = __builtin_bit_cast(unsigned short, lo);
    unsigned short b = __builtin_bit_cast(unsigned short, hi);
    return (unsigned)a | ((unsigned)b << 16);
}

// ---------------------------------------------------------------------------
// R14: 16x16x32 MFMA. The 32x32 shape's 16-reg accumulator is what the
// compiler parks in AGPRs -> every fold element pays accvgpr traffic (the
// invariant ~4-6x per-tile tax across R6-R13; R12: VALU ~58 instr/tile vs
// ~10 written, VGPR_Count=36 impossible for 64 live floats). The 16x16x32
// accumulator is 4 regs -> stays VGPR, fold = plain v_min3, no pins.
//
// Packing (K=32, lane-groups g=lane>>4, 8 k-slots each; A row=lane&15,
// B col=lane&15; only sum consistency between A and B matters, so exact
// k order is irrelevant):
//   g0: A=[-oh0,-oh1,-oh2, -ol0,-ol1,-ol2, onh, onl]
//       B=[ ih0, ih1, ih2,  ih0, ih1, ih2,   1,   1]
//   g1: A=[-oh0,-oh1,-oh2, 1, 1, 0,0,0]
//       B=[ il0, il1, il2, hh, hl, 0,0,0]
//   g2,g3: A = 0 -> B don't-care: lanes>=32 re-read lane&31's address
//          (LDS same-address broadcast, free).
// D = on + h - (oh.ih + ol.ih + oh.il) = d^2/2 (error ~1e-6, as verified).
// C/D layout [m89]: col=lane&15, row=(lane>>4)*4+reg.
// Per 256-pair tile: 1 ds_read_b128 + 1 MFMA + 2 v_min3 (pair-folded).
// ---------------------------------------------------------------------------
__global__ __launch_bounds__(BLK, 5) void chamfer_mfma_kernel(
    const float* __restrict__ x, const float* __restrict__ y,
    float* __restrict__ ws0, float* __restrict__ ws1,
    float* __restrict__ out)
{
    const int b    = blockIdx.y;
    const int xc   = blockIdx.x;          // 0..63 outer-chunk
    const int role = blockIdx.z >> 2;     // 0: outer=x, 1: outer=y
    const int slab = blockIdx.z & 3;      // 0..3 inner-slab
    const int tid  = threadIdx.x;
    const int lane = tid & 63;
    const int wave = tid >> 6;            // 0..3
    const int l15  = lane & 15;
    const int g    = lane >> 4;           // 0..3 k-group
    const int l31  = lane & 31;

    const float* __restrict__ outer = role ? y : x;
    const float* __restrict__ inner = role ? x : y;
    float* __restrict__ ws = role ? ws1 : ws0;

    if (xc == 0 && blockIdx.z == 0 && tid == 0) out[b] = 0.0f;

    __shared__ uint4 ldsb[NT16 * 32];     // 64 tiles x 32 entries = 32 KB

    // ---- A fragment (this wave's 16 outer rows; 4 lanes per row)
    const int row = xc * ROWS_PER_BLOCK + wave * 16 + l15;
    const float* op = outer + ((size_t)b * S + row) * 3;
    const float o0 = op[0], o1 = op[1], o2 = op[2];
    const float on = 0.5f * (o0 * o0 + o1 * o1 + o2 * o2);
    const _Float16 oh0 = (_Float16)o0, oh1 = (_Float16)o1, oh2 = (_Float16)o2;
    const _Float16 ol0 = (_Float16)(o0 - (float)oh0);
    const _Float16 ol1 = (_Float16)(o1 - (float)oh1);
    const _Float16 ol2 = (_Float16)(o2 - (float)oh2);
    const _Float16 onh = (_Float16)on;
    const _Float16 onl = (_Float16)(on - (float)onh);
    const _Float16 h1c = (_Float16)1.0f;
    const _Float16 h0c = (_Float16)0.0f;
    half8 afrag;
    if (g == 0) {
        afrag[0] = -oh0; afrag[1] = -oh1; afrag[2] = -oh2;
        afrag[3] = -ol0; afrag[4] = -ol1; afrag[5] = -ol2;
        afrag[6] = onh;  afrag[7] = onl;
    } else if (g == 1) {
        afrag[0] = -oh0; afrag[1] = -oh1; afrag[2] = -oh2;
        afrag[3] = h1c;  afrag[4] = h1c;
        afrag[5] = h0c;  afrag[6] = h0c;  afrag[7] = h0c;
    } else {
        afrag[0] = h0c; afrag[1] = h0c; afrag[2] = h0c; afrag[3] = h0c;
        afrag[4] = h0c; afrag[5] = h0c; afrag[6] = h0c; afrag[7] = h0c;
    }

    // ---- stage the FULL slab once: 4 points per thread, 2 uint4 each
    const float* isrc = inner + ((size_t)b * S + slab * YSPAN) * 3;
#pragma unroll
    for (int k = 0; k < YSPAN / BLK; ++k) {
        const int p = k * BLK + tid;               // 0..1023
        const float* ip = isrc + (size_t)p * 3;
        const float i0 = ip[0], i1 = ip[1], i2 = ip[2];
        const float h  = 0.5f * (i0 * i0 + i1 * i1 + i2 * i2);
        const _Float16 a0 = (_Float16)i0, a1 = (_Float16)i1, a2 = (_Float16)i2;
        const _Float16 c0 = (_Float16)(i0 - (float)a0);
        const _Float16 c1 = (_Float16)(i1 - (float)a1);
        const _Float16 c2 = (_Float16)(i2 - (float)a2);
        const _Float16 hh = (_Float16)h;
        const _Float16 hl = (_Float16)(h - (float)hh);
        const int t = p >> 4, col = p & 15;
        ldsb[t * 32 + col]      = make_uint4(pack2(a0, a1), pack2(a2, a0),
                                             pack2(a1, a2), pack2(h1c, h1c));
        ldsb[t * 32 + 16 + col] = make_uint4(pack2(c0, c1), pack2(c2, hh),
                                             pack2(hl, h0c), pack2(h0c, h0c));
    }

    __syncthreads();

    // ---- 64 tiles, barrier-free: ds_read_b128 + MFMA + pair min3 fold
    floatx4 run;
#pragma unroll
    for (int r = 0; r < 4; ++r) run[r] = 3.0e38f;
    const floatx4 z4 = {};

#pragma unroll 2
    for (int t = 0; t < NT16; t += 2) {
        const uint4 q0 = ldsb[t * 32 + l31];       // lanes>=32 broadcast-dup
        const uint4 q1 = ldsb[(t + 1) * 32 + l31];
        const floatx4 d0 = __builtin_amdgcn_mfma_f32_16x16x32_f16(
            afrag, __builtin_bit_cast(half8, q0), z4, 0, 0, 0);
        const floatx4 d1 = __builtin_amdgcn_mfma_f32_16x16x32_f16(
            afrag, __builtin_bit_cast(half8, q1), z4, 0, 0, 0);
#pragma unroll
        for (int r = 0; r < 4; ++r)
            run[r] = fminf(fminf(d0[r], d1[r]), run[r]);
    }

    // ---- flush: rows live as (g*4+r) at col=l15; min across 16 cols
#pragma unroll
    for (int r = 0; r < 4; ++r) {
        float v = run[r];
        v = fminf(v, __shfl_xor(v, 1));
        v = fminf(v, __shfl_xor(v, 2));
        v = fminf(v, __shfl_xor(v, 4));
        v = fminf(v, __shfl_xor(v, 8));
        run[r] = v;
    }
    if (l15 == 0) {
        float* w = ws + ((size_t)slab * BATCH + b) * S
                      + xc * ROWS_PER_BLOCK + wave * 16 + g * 4;
#pragma unroll
        for (int r = 0; r < 4; ++r) w[r] = run[r];
    }
}

// ---------------------------------------------------------------------------
// Pass 2: grid (RSEG, BATCH). Each block owns 256 rows of batch b:
// fold ws0 and ws1 over their 4 inner-slabs (coalesced), clamp, sqrt-sum,
// one atomicAdd per block into out[b] (out zeroed by pass 1).
// ---------------------------------------------------------------------------
#define RSEG   (S / BLK)            // 16 segments of 256 rows
__global__ __launch_bounds__(BLK) void chamfer_reduce_kernel(
    const float* __restrict__ ws0, const float* __restrict__ ws1,
    float* __restrict__ out)
{
    const int b   = blockIdx.y;
    const int i   = blockIdx.x * BLK + threadIdx.x;   // row index
    const int tid = threadIdx.x;

    float mx = 3.0e38f, my = 3.0e38f;
#pragma unroll
    for (int sl = 0; sl < YC_N; ++sl) {
        mx = fminf(mx, ws0[((size_t)sl * BATCH + b) * S + i]);
        my = fminf(my, ws1[((size_t)sl * BATCH + b) * S + i]);
    }

    float s = sqrtf(2.0f * fmaxf(mx, 0.0f)) + sqrtf(2.0f * fmaxf(my, 0.0f));

    __shared__ float red[BLK];
    red[tid] = s;
    __syncthreads();
    for (int off = BLK / 2; off > 0; off >>= 1) {
        if (tid < off) red[tid] += red[tid + off];
        __syncthreads();
    }
    if (tid == 0) atomicAdd(&out[b], red[0] * (0.5f / (float)S));
}

// ---------------------------------------------------------------------------
// Fallback (no workspace): scalar full-range kernel, atomicAdd into out.
// ---------------------------------------------------------------------------
#define P   8
#define FMC 1024
#define OUTER_PER_BLK (BLK * P)
__global__ __launch_bounds__(BLK) void chamfer_full_kernel(
    const float* __restrict__ x, const float* __restrict__ y,
    float* __restrict__ out)
{
    const int role = blockIdx.z;
    const int b    = blockIdx.y;
    const int oc   = blockIdx.x;
    const float* __restrict__ outer = (role == 0) ? x : y;
    const float* __restrict__ inner = (role == 0) ? y : x;
    const int tid = threadIdx.x;
    const int n0  = oc * OUTER_PER_BLK;

    __shared__ float4 lds[FMC];

    float nx0[P], nx1[P], nx2[P], xn[P], tmin[P];
#pragma unroll
    for (int p = 0; p < P; ++p) {
        const int n = n0 + p * BLK + tid;
        const float* xp = outer + ((size_t)b * S + n) * 3;
        const float a0 = xp[0], a1 = xp[1], a2 = xp[2];
        nx0[p] = -a0; nx1[p] = -a1; nx2[p] = -a2;
        xn[p]  = a0 * a0 + a1 * a1 + a2 * a2;
        tmin[p] = 3.0e38f;
    }

    for (int m0 = 0; m0 < S; m0 += FMC) {
        __syncthreads();
        for (int i = tid; i < FMC; i += BLK) {
            const float* yp = inner + ((size_t)b * S + m0 + i) * 3;
            const float a0 = yp[0], a1 = yp[1], a2 = yp[2];
            lds[i] = make_float4(a0, a1, a2,
                                 0.5f * (a0 * a0 + a1 * a1 + a2 * a2));
        }
        __syncthreads();
#pragma unroll 4
        for (int j = 0; j < FMC; ++j) {
            const float4 v = lds[j];
#pragma unroll
            for (int p = 0; p < P; ++p) {
                const float t = fmaf(nx0[p], v.x,
                                 fmaf(nx1[p], v.y,
                                  fmaf(nx2[p], v.z, v.w)));
                tmin[p] = fminf(tmin[p], t);
            }
        }
    }

    float s = 0.0f;
#pragma unroll
    for (int p = 0; p < P; ++p)
        s += sqrtf(fmaxf(fmaf(2.0f, tmin[p], xn[p]), 0.0f));

    __shared__ float red[BLK];
    red[tid] = s;
    __syncthreads();
    for (int off = BLK / 2; off > 0; off >>= 1) {
        if (tid < off) red[tid] += red[tid + off];
        __syncthreads();
    }
    if (tid == 0) atomicAdd(&out[b], red[0] * (0.5f / (float)S));
}

extern "C" void kernel_launch(void* const* d_in, const int* in_sizes, int n_in,
                              void* d_out, int out_size, void* d_ws, size_t ws_size,
                              hipStream_t stream) {
    const float* x = (const float*)d_in[0];
    const float* y = (const float*)d_in[1];
    float* out = (float*)d_out;

    // ws0, ws1: [YC_N][BATCH][S] floats each (row-min partials per slab)
    const size_t n_ws = (size_t)YC_N * BATCH * S;
    const size_t need = 2 * n_ws * sizeof(float);   // 2 MB
    if (ws_size >= need) {
        float* ws0 = (float*)d_ws;
        float* ws1 = ws0 + n_ws;
        chamfer_mfma_kernel<<<dim3(XC_N, BATCH, 2 * YC_N), BLK, 0, stream>>>(
            x, y, ws0, ws1, out);
        chamfer_reduce_kernel<<<dim3(RSEG, BATCH), BLK, 0, stream>>>(
            ws0, ws1, out);
    } else {
        hipMemsetAsync(d_out, 0, BATCH * sizeof(float), stream);
        chamfer_full_kernel<<<dim3(S / OUTER_PER_BLK, BATCH, 2), BLK, 0, stream>>>(
            x, y, out);
    }
}